// Round 8
// baseline (182.035 us; speedup 1.0000x reference)
//
#include <hip/hip_runtime.h>

#define BN 32
#define BC 512
#define BH 64
#define BW 64

typedef float vf4 __attribute__((ext_vector_type(4)));

// ---------------------------------------------------------------- kernel 1
// 4 channels per block (4096 blocks). Wave w handles channel cb+w:
// pure-shuffle row/col means, 16 float4 loads/thread in flight.
// Also zeroes the k_att flags (block 0).
__global__ __launch_bounds__(256) void k_means(const float* __restrict__ x,
                                               float* __restrict__ ycat,
                                               unsigned* __restrict__ flags) {
    int b4 = blockIdx.x;
    int t = threadIdx.x;
    if (b4 == 0 && t < BN) flags[t] = 0u;        // consumed by k_att (next kernel)
    int w = t >> 6, j = t & 63;                  // wave, lane
    const vf4* x4 = (const vf4*)(x + ((size_t)b4 * 4 + w) * (BH * BW));
    __shared__ float red[4][128];

    float cx = 0.f, cy = 0.f, cz = 0.f, cw = 0.f;
    #pragma unroll
    for (int i = 0; i < 16; ++i) {
        vf4 v = x4[j + 64 * i];
        float s = v.x + v.y + v.z + v.w;         // row (j>>4)+4i, 16 lanes share
        s += __shfl_down(s, 8, 16);
        s += __shfl_down(s, 4, 16);
        s += __shfl_down(s, 2, 16);
        s += __shfl_down(s, 1, 16);
        if ((j & 15) == 0) red[w][(j >> 4) + 4 * i] = s * (1.0f / 64.0f);
        cx += v.x; cy += v.y; cz += v.z; cw += v.w;   // cols 4*(j&15)..+3
    }
    // combine col partials across lanes {j, j^16, j^32, j^48}
    cx += __shfl_xor(cx, 16, 64); cx += __shfl_xor(cx, 32, 64);
    cy += __shfl_xor(cy, 16, 64); cy += __shfl_xor(cy, 32, 64);
    cz += __shfl_xor(cz, 16, 64); cz += __shfl_xor(cz, 32, 64);
    cw += __shfl_xor(cw, 16, 64); cw += __shfl_xor(cw, 32, 64);
    if (j < 16) {
        vf4 cv = {cx, cy, cz, cw};
        cv *= (1.0f / 64.0f);
        ((vf4*)&red[w][64])[j] = cv;             // cols 4j..4j+3
    }
    __syncthreads();
    size_t base = (size_t)b4 * 512;              // 4 channels x 128
    #pragma unroll
    for (int i = 0; i < 2; ++i) {
        int idx = t + i * 256;
        ycat[base + idx] = ((float*)red)[idx];
    }
}

// ---------------------------------------------------------------- kernel 2
// merged conv1 + score with in-kernel flag sync. 256 blocks = (n, j).
// Phase 1: conv1 for (n, lc=j) -> yl global. Phase 2 (after flag[n]==8):
// q/k/v -> scores -> softmax -> z -> zbuf[n][d][h].
__global__ __launch_bounds__(256) void k_att(
    const float* __restrict__ ycat,
    const float* __restrict__ w_cv1, const float* __restrict__ b_cv1,
    const float* __restrict__ w_q, const float* __restrict__ b_q,
    const float* __restrict__ w_k, const float* __restrict__ b_k,
    const float* __restrict__ w_v, const float* __restrict__ b_v,
    float* __restrict__ yl, float* __restrict__ zbuf,
    unsigned* __restrict__ flags) {
    int bid = blockIdx.x;
    int nl = bid >> 3, jc = bid & 7;
    int t = threadIdx.x;
    __shared__ float smem[16384];                // 64 KB, phase-unioned

    // ---- phase 1: conv1 for (n=nl, lc=jc) ----
    {
        float* yc_s = smem;                      // [512][16]
        float* w_s  = smem + 8192;               // [16][512]
        const float4* ysrc = (const float4*)(ycat + (size_t)nl * (BC * 128));
        float4* ycdst = (float4*)yc_s;
        for (int i = 0; i < 8; ++i) {            // 2048 float4
            int i4 = t + i * 256;
            int c = i4 >> 2, q = i4 & 3;
            ycdst[c * 4 + q] = ysrc[c * 32 + jc * 4 + q];
        }
        const float4* wsrc = (const float4*)w_cv1;
        float4* wdst = (float4*)w_s;
        for (int i = 0; i < 8; ++i) wdst[t + i * 256] = wsrc[t + i * 256];
        __syncthreads();

        int m = t >> 4, l = t & 15;
        float acc = b_cv1[m];
        #pragma unroll 8
        for (int c = 0; c < 512; ++c) acc += w_s[m * 512 + c] * yc_s[c * 16 + l];
        yl[(size_t)nl * 2048 + m * 128 + jc * 16 + l] = acc;
    }
    __threadfence();                             // flush yl to device scope
    __syncthreads();
    if (t == 0) {
        atomicAdd(&flags[nl], 1u);
        while (atomicAdd(&flags[nl], 0u) < 8u) __builtin_amdgcn_s_sleep(2);
    }
    __syncthreads();
    __threadfence();                             // acquire

    // ---- phase 2: score for (n=nl, hc=jc) ----
    float* yl_s   = smem;                        // [16][128]
    float* wq_s   = smem + 2048;
    float* wk_s   = smem + 2304;
    float* wv_s   = smem + 2560;
    float* q_s    = smem + 2816;                 // [16][8]
    float* k_s    = smem + 2944;                 // [16][64]
    float* v_s    = smem + 3968;                 // [16][64]
    float* attn_s = smem + 4992;                 // [8][64]

    {
        const float4* s4 = (const float4*)(yl + (size_t)nl * 2048);
        float4* d4 = (float4*)yl_s;
        for (int i = 0; i < 2; ++i) d4[t + i * 256] = s4[t + i * 256];
        wq_s[t] = w_q[t]; wk_s[t] = w_k[t]; wv_s[t] = w_v[t];
    }
    __syncthreads();

    if (t < 128) {                               // q for this h-chunk
        int d = t >> 3, hh = t & 7, h = jc * 8 + hh;
        float a = b_q[d];
        #pragma unroll
        for (int m = 0; m < 16; ++m) a += wq_s[d * 16 + m] * yl_s[m * 128 + h];
        q_s[d * 8 + hh] = a;
    }
    for (int i = 0; i < 4; ++i) {                // k, v full
        int idx = t + i * 256;
        int d = idx >> 6, ww = idx & 63;
        float ak = b_k[d], av = b_v[d];
        #pragma unroll
        for (int m = 0; m < 16; ++m) {
            float yv = yl_s[m * 128 + 64 + ww];
            ak += wk_s[d * 16 + m] * yv;
            av += wv_s[d * 16 + m] * yv;
        }
        k_s[d * 64 + ww] = ak; v_s[d * 64 + ww] = av;
    }
    __syncthreads();

    for (int i = 0; i < 2; ++i) {                // scores, SCALE = 0.25
        int idx = t + i * 256;
        int hh = idx >> 6, ww = idx & 63;
        float s = 0.f;
        #pragma unroll
        for (int d = 0; d < 16; ++d) s += q_s[d * 8 + hh] * k_s[d * 64 + ww];
        attn_s[hh * 64 + ww] = s * 0.25f;
    }
    __syncthreads();

    {   // softmax: 8 rows, 32 lanes each
        int r = t >> 5, lane = t & 31;
        float a0 = attn_s[r * 64 + lane], a1 = attn_s[r * 64 + lane + 32];
        float mx = fmaxf(a0, a1);
        for (int off = 16; off >= 1; off >>= 1) mx = fmaxf(mx, __shfl_xor(mx, off, 32));
        float e0 = __expf(a0 - mx), e1 = __expf(a1 - mx);
        float sm = e0 + e1;
        for (int off = 16; off >= 1; off >>= 1) sm += __shfl_xor(sm, off, 32);
        float inv = 1.0f / sm;
        attn_s[r * 64 + lane] = e0 * inv;
        attn_s[r * 64 + lane + 32] = e1 * inv;
    }
    __syncthreads();

    if (t < 128) {                               // z[d][hh] -> zbuf[n][d][h]
        int d = t >> 3, hh = t & 7;
        float a = 0.f;
        #pragma unroll 8
        for (int ww = 0; ww < 64; ++ww) a += attn_s[hh * 64 + ww] * v_s[d * 64 + ww];
        zbuf[(size_t)nl * 1024 + d * 64 + jc * 8 + hh] = a;
    }
}

// ---------------------------------------------------------------- kernel 3
// fused proj + sigmoid + gated copy. 2048 blocks; block = (n, 8-ch chunk).
__global__ __launch_bounds__(256) void k_gatemul(
    const float* __restrict__ x, const float* __restrict__ zbuf,
    const float* __restrict__ w_proj, const float* __restrict__ b_proj,
    float* __restrict__ out) {
    int rid = blockIdx.x;
    int n = rid >> 6, cb = rid & 63;             // 8 channels per block
    int t = threadIdx.x;
    __shared__ float z_s[16][64];
    __shared__ float gate_s[512];

    for (int i = 0; i < 4; ++i) {
        int idx = t + i * 256;
        ((float*)z_s)[idx] = zbuf[(size_t)n * 1024 + idx];
    }
    __syncthreads();
    #pragma unroll
    for (int i = 0; i < 2; ++i) {
        int idx = t + i * 256;                   // 512 = 8c x 64h
        int c = cb * 8 + (idx >> 6), hh = idx & 63;
        float a = b_proj[c];
        #pragma unroll
        for (int m = 0; m < 16; ++m) a += w_proj[c * 16 + m] * z_s[m][hh];
        gate_s[idx] = 1.0f / (1.0f + __expf(-a));
    }
    __syncthreads();

    size_t base = (size_t)rid * 8192;            // float4 units
    const vf4* x4 = (const vf4*)x + base;
    vf4* o4 = (vf4*)out + base;
    #pragma unroll
    for (int i = 0; i < 32; ++i) {
        int f = t + i * 256;
        float g = gate_s[f >> 4];
        vf4 v = x4[f];
        v *= g;
        __builtin_nontemporal_store(v, &o4[f]);
    }
}

extern "C" void kernel_launch(void* const* d_in, const int* in_sizes, int n_in,
                              void* d_out, int out_size, void* d_ws, size_t ws_size,
                              hipStream_t stream) {
    const float* x      = (const float*)d_in[0];
    const float* w_cv1  = (const float*)d_in[1];
    const float* b_cv1  = (const float*)d_in[2];
    const float* w_q    = (const float*)d_in[3];
    const float* b_q    = (const float*)d_in[4];
    const float* w_k    = (const float*)d_in[5];
    const float* b_k    = (const float*)d_in[6];
    const float* w_v    = (const float*)d_in[7];
    const float* b_v    = (const float*)d_in[8];
    const float* w_proj = (const float*)d_in[9];
    const float* b_proj = (const float*)d_in[10];
    float* out = (float*)d_out;

    float* ycat = (float*)d_ws;                          // 32*512*128 = 8 MB
    float* yl   = ycat + (size_t)BN * BC * 128;          // 32*16*128
    float* zbuf = yl + (size_t)BN * 2048;                // 32*16*64
    unsigned* flags = (unsigned*)(zbuf + (size_t)BN * 1024);  // 32 u32

    hipLaunchKernelGGL(k_means, dim3(BN * BC / 4), dim3(256), 0, stream,
                       x, ycat, flags);
    hipLaunchKernelGGL(k_att, dim3(BN * 8), dim3(256), 0, stream,
                       ycat, w_cv1, b_cv1, w_q, b_q, w_k, b_k, w_v, b_v,
                       yl, zbuf, flags);
    hipLaunchKernelGGL(k_gatemul, dim3(BN * 64), dim3(256), 0, stream,
                       x, zbuf, w_proj, b_proj, out);
}

// Round 9
// 139.184 us; speedup vs baseline: 1.3079x; 1.3079x over previous
//
#include <hip/hip_runtime.h>

#define BN 32
#define BC 512
#define BH 64
#define BW 64

typedef float vf4 __attribute__((ext_vector_type(4)));

// ---------------------------------------------------------------- kernel 1
// one block per (n,c): row/col means of the 64x64 tile
// -> ycat[n][c][0:64]=rowmean(over w), [64:128]=colmean(over h)
__global__ __launch_bounds__(256) void k_means(const float* __restrict__ x,
                                               float* __restrict__ ycat) {
    int bc = blockIdx.x;                         // n*512 + c
    const float4* x4 = (const float4*)(x + (size_t)bc * (BH * BW));
    __shared__ float rowsum[64];
    __shared__ float colsum[64];
    __shared__ float colpart[256][5];
    int t = threadIdx.x;

    float cx = 0.f, cy = 0.f, cz = 0.f, cw = 0.f;
    for (int i = 0; i < 4; ++i) {
        int f = t + i * 256;                     // float4 index 0..1023
        float4 v = x4[f];
        float s = v.x + v.y + v.z + v.w;         // 16 lanes share row f>>4
        s += __shfl_down(s, 8, 16);
        s += __shfl_down(s, 4, 16);
        s += __shfl_down(s, 2, 16);
        s += __shfl_down(s, 1, 16);
        if ((t & 15) == 0) rowsum[f >> 4] = s;
        cx += v.x; cy += v.y; cz += v.z; cw += v.w;   // cols (t&15)*4..+3
    }
    colpart[t][0] = cx; colpart[t][1] = cy; colpart[t][2] = cz; colpart[t][3] = cw;
    __syncthreads();
    if (t < 64) {
        int base = t >> 2, comp = t & 3;         // column t
        float s = 0.f;
        for (int g = 0; g < 16; ++g) s += colpart[base + 16 * g][comp];
        colsum[t] = s;
    }
    __syncthreads();
    if (t < 128) {
        float m = (t < 64 ? rowsum[t] : colsum[t - 64]) * (1.0f / 64.0f);
        ycat[(size_t)bc * 128 + t] = m;
    }
}

// ---------------------------------------------------------------- kernel 2
// conv1: y[n][m][l] = b_cv1[m] + sum_c w_cv1[m][c]*ycat[n][c][l]
// grid: BN*8 blocks; block = (n, l-chunk of 16). One output/thread.
__global__ __launch_bounds__(256) void k_conv1(const float* __restrict__ ycat,
                                               const float* __restrict__ w_cv1,
                                               const float* __restrict__ b_cv1,
                                               float* __restrict__ yl) {
    int bid = blockIdx.x;
    int nl = bid >> 3, lc = bid & 7;
    int t = threadIdx.x;
    __shared__ float yc_s[512][16];              // 32 KB
    __shared__ float w_s[16][512];               // 32 KB

    const float4* ysrc = (const float4*)(ycat + (size_t)nl * (BC * 128));
    float4* ycdst = (float4*)&yc_s[0][0];
    for (int i = 0; i < 8; ++i) {                // 2048 float4
        int i4 = t + i * 256;
        int c = i4 >> 2, j = i4 & 3;
        ycdst[c * 4 + j] = ysrc[c * 32 + lc * 4 + j];
    }
    const float4* wsrc = (const float4*)w_cv1;
    float4* wdst = (float4*)&w_s[0][0];
    for (int i = 0; i < 8; ++i) wdst[t + i * 256] = wsrc[t + i * 256];
    __syncthreads();

    int m = t >> 4, l = t & 15;
    float acc = b_cv1[m];
    #pragma unroll 8
    for (int c = 0; c < 512; ++c) acc += w_s[m][c] * yc_s[c][l];
    yl[(size_t)nl * 2048 + m * 128 + lc * 16 + l] = acc;
}

// ---------------------------------------------------------------- kernel 3
// q/k/v -> scores -> softmax -> z -> zbuf[n][d][h]   (no proj here)
// grid: BN*8 blocks; block = (n, h-chunk of 8).
__global__ __launch_bounds__(256) void k_score(
    const float* __restrict__ yl,
    const float* __restrict__ w_q, const float* __restrict__ b_q,
    const float* __restrict__ w_k, const float* __restrict__ b_k,
    const float* __restrict__ w_v, const float* __restrict__ b_v,
    float* __restrict__ zbuf) {
    int bid = blockIdx.x;
    int nl = bid >> 3, hc = bid & 7;
    int t = threadIdx.x;
    __shared__ float yl_s[16][128];              // 8 KB
    __shared__ float wq_s[256], wk_s[256], wv_s[256];
    __shared__ float q_s[16][8];
    __shared__ float k_s[16][64], v_s[16][64];   // 8 KB
    __shared__ float attn_s[8][64];              // 2 KB

    {   // stage yl[n] + small weight mats
        const float4* s4 = (const float4*)(yl + (size_t)nl * 2048);
        float4* d4 = (float4*)&yl_s[0][0];
        for (int i = 0; i < 2; ++i) d4[t + i * 256] = s4[t + i * 256];
        wq_s[t] = w_q[t]; wk_s[t] = w_k[t]; wv_s[t] = w_v[t];
    }
    __syncthreads();

    // q for this h-chunk
    if (t < 128) {
        int d = t >> 3, hh = t & 7, h = hc * 8 + hh;
        float a = b_q[d];
        #pragma unroll
        for (int m = 0; m < 16; ++m) a += wq_s[d * 16 + m] * yl_s[m][h];
        q_s[d][hh] = a;
    }
    // k, v full
    for (int i = 0; i < 4; ++i) {
        int idx = t + i * 256;
        int d = idx >> 6, ww = idx & 63;
        float ak = b_k[d], av = b_v[d];
        #pragma unroll
        for (int m = 0; m < 16; ++m) {
            float yv = yl_s[m][64 + ww];
            ak += wk_s[d * 16 + m] * yv;
            av += wv_s[d * 16 + m] * yv;
        }
        k_s[d][ww] = ak; v_s[d][ww] = av;
    }
    __syncthreads();

    // scores (8h x 64w), SCALE = 0.25
    for (int i = 0; i < 2; ++i) {
        int idx = t + i * 256;
        int hh = idx >> 6, ww = idx & 63;
        float s = 0.f;
        #pragma unroll
        for (int d = 0; d < 16; ++d) s += q_s[d][hh] * k_s[d][ww];
        attn_s[hh][ww] = s * 0.25f;
    }
    __syncthreads();

    // softmax: 8 rows, 32 lanes each
    {
        int r = t >> 5, lane = t & 31;
        float a0 = attn_s[r][lane], a1 = attn_s[r][lane + 32];
        float mx = fmaxf(a0, a1);
        for (int off = 16; off >= 1; off >>= 1) mx = fmaxf(mx, __shfl_xor(mx, off, 32));
        float e0 = __expf(a0 - mx), e1 = __expf(a1 - mx);
        float sm = e0 + e1;
        for (int off = 16; off >= 1; off >>= 1) sm += __shfl_xor(sm, off, 32);
        float inv = 1.0f / sm;
        attn_s[r][lane] = e0 * inv;
        attn_s[r][lane + 32] = e1 * inv;
    }
    __syncthreads();

    // z[d][hh] = sum_w attn[hh][w] * v[d][w]  -> zbuf[n][d][h]
    if (t < 128) {
        int d = t >> 3, hh = t & 7;
        float a = 0.f;
        #pragma unroll 8
        for (int ww = 0; ww < 64; ++ww) a += attn_s[hh][ww] * v_s[d][ww];
        zbuf[(size_t)nl * 1024 + d * 64 + hc * 8 + hh] = a;
    }
}

// ---------------------------------------------------------------- kernel 4
// fused proj + sigmoid + gated copy. 2048 blocks; block = (n, 8-ch chunk).
// First 8 x-loads are issued BEFORE the gate phase so the zbuf load, gate
// math, and both barriers hide under HBM latency of the x stream.
__global__ __launch_bounds__(256) void k_gatemul(
    const float* __restrict__ x, const float* __restrict__ zbuf,
    const float* __restrict__ w_proj, const float* __restrict__ b_proj,
    float* __restrict__ out) {
    int rid = blockIdx.x;
    int n = rid >> 6, cb = rid & 63;             // 8 channels per block
    int t = threadIdx.x;
    __shared__ float z_s[16][64];
    __shared__ float gate_s[512];

    size_t base = (size_t)rid * 8192;            // float4 units (8*64*64/4)
    const vf4* x4 = (const vf4*)x + base;
    vf4* o4 = (vf4*)out + base;

    // prefetch first 8 float4 per thread (issued before any LDS/barrier)
    vf4 xv[8];
    #pragma unroll
    for (int i = 0; i < 8; ++i) xv[i] = x4[t + i * 256];

    for (int i = 0; i < 4; ++i) {
        int idx = t + i * 256;
        ((float*)z_s)[idx] = zbuf[(size_t)n * 1024 + idx];
    }
    __syncthreads();
    #pragma unroll
    for (int i = 0; i < 2; ++i) {
        int idx = t + i * 256;                   // 512 = 8c x 64h
        int c = cb * 8 + (idx >> 6), hh = idx & 63;
        float a = b_proj[c];
        #pragma unroll
        for (int m = 0; m < 16; ++m) a += w_proj[c * 16 + m] * z_s[m][hh];
        gate_s[idx] = 1.0f / (1.0f + __expf(-a));
    }
    __syncthreads();

    #pragma unroll
    for (int i = 0; i < 8; ++i) {                // drain the prefetched regs
        int f = t + i * 256;
        vf4 v = xv[i] * gate_s[f >> 4];
        __builtin_nontemporal_store(v, &o4[f]);
    }
    #pragma unroll
    for (int i = 8; i < 32; ++i) {               // stream the rest
        int f = t + i * 256;
        float g = gate_s[f >> 4];
        vf4 v = x4[f];
        v *= g;
        __builtin_nontemporal_store(v, &o4[f]);
    }
}

extern "C" void kernel_launch(void* const* d_in, const int* in_sizes, int n_in,
                              void* d_out, int out_size, void* d_ws, size_t ws_size,
                              hipStream_t stream) {
    const float* x      = (const float*)d_in[0];
    const float* w_cv1  = (const float*)d_in[1];
    const float* b_cv1  = (const float*)d_in[2];
    const float* w_q    = (const float*)d_in[3];
    const float* b_q    = (const float*)d_in[4];
    const float* w_k    = (const float*)d_in[5];
    const float* b_k    = (const float*)d_in[6];
    const float* w_v    = (const float*)d_in[7];
    const float* b_v    = (const float*)d_in[8];
    const float* w_proj = (const float*)d_in[9];
    const float* b_proj = (const float*)d_in[10];
    float* out = (float*)d_out;

    float* ycat = (float*)d_ws;                          // 32*512*128 = 8 MB
    float* yl   = ycat + (size_t)BN * BC * 128;          // 32*16*128  = 256 KB
    float* zbuf = yl + (size_t)BN * 2048;                // 32*16*64   = 128 KB

    hipLaunchKernelGGL(k_means, dim3(BN * BC), dim3(256), 0, stream, x, ycat);
    hipLaunchKernelGGL(k_conv1, dim3(BN * 8), dim3(256), 0, stream,
                       ycat, w_cv1, b_cv1, yl);
    hipLaunchKernelGGL(k_score, dim3(BN * 8), dim3(256), 0, stream,
                       yl, w_q, b_q, w_k, b_k, w_v, b_v, zbuf);
    hipLaunchKernelGGL(k_gatemul, dim3(BN * 64), dim3(256), 0, stream,
                       x, zbuf, w_proj, b_proj, out);
}